// Round 9
// baseline (1006.540 us; speedup 1.0000x reference)
//
#include <hip/hip_runtime.h>
#include <hip/hip_bf16.h>

typedef __hip_bfloat16 bf16;
using bf16x8 = __attribute__((ext_vector_type(8))) short;
using f32x4  = __attribute__((ext_vector_type(4))) float;

#define S_LEN 1024
#define CDIM  576
#define NHEAD 8
#define DKH   72
#define BATCH 4
#define MROWS 4096   // B*S
#define FFDIM 2304
#define QKVN  1728   // 3*C
#define VT_D  80     // vT padded d
#define VT_LS (VT_D * S_LEN)

// async global->LDS, 16B per lane, lane-ordered LDS destination
__device__ __forceinline__ void gload16(const void* g, void* l) {
  __builtin_amdgcn_global_load_lds(
      (const __attribute__((address_space(1))) unsigned int*)g,
      (__attribute__((address_space(3))) unsigned int*)l, 16, 0, 0);
}

// float -> bf16 bits (RNE), pure integer math (type-safe for LDS punning)
__device__ __forceinline__ short f2bf_bits(float x) {
  unsigned int u = __float_as_uint(x);
  u += 0x7fffu + ((u >> 16) & 1u);
  return (short)(u >> 16);
}

// ---------------- weight transpose + fp32->bf16 convert ----------------
__global__ __launch_bounds__(256) void transpose_cvt(
    const float* __restrict__ in, bf16* __restrict__ out, int K, int N,
    size_t in_ls, size_t out_ls) {
  __shared__ float tile[32][33];
  const float* inl = in + (size_t)blockIdx.z * in_ls;
  bf16* outl = out + (size_t)blockIdx.z * out_ls;
  int n0 = blockIdx.x * 32, k0 = blockIdx.y * 32;
  int tx = threadIdx.x & 31, ty = threadIdx.x >> 5;
#pragma unroll
  for (int i = 0; i < 32; i += 8)
    tile[ty + i][tx] = inl[(size_t)(k0 + ty + i) * N + (n0 + tx)];
  __syncthreads();
#pragma unroll
  for (int i = 0; i < 32; i += 8)
    outl[(size_t)(n0 + ty + i) * K + (k0 + tx)] = __float2bfloat16(tile[tx][ty + i]);
}

// ---------------- V^T builder: qkvb V-slice [s][dh] -> vT [bh][dh][s] ----------------
// grid (32 s-tiles, 3 d-tiles, 32 bh), block 256
__global__ __launch_bounds__(256) void vt_kernel(
    const bf16* __restrict__ qkvb, bf16* __restrict__ vT) {
  __shared__ short tile[32][33];
  int bh = blockIdx.z, b = bh >> 3, h = bh & 7;
  int s0 = blockIdx.x * 32, d0 = blockIdx.y * 32;
  int tx = threadIdx.x & 31, ty = threadIdx.x >> 5;
  const short* src = (const short*)qkvb;
  short* dst = (short*)vT + (size_t)bh * VT_LS;
#pragma unroll
  for (int i = 0; i < 32; i += 8) {
    int s = s0 + ty + i, dh = d0 + tx;
    short v = 0;
    if (dh < DKH) v = src[(size_t)(b * S_LEN + s) * QKVN + 2 * CDIM + h * DKH + dh];
    tile[ty + i][tx] = v;
  }
  __syncthreads();
#pragma unroll
  for (int i = 0; i < 32; i += 8) {
    int dh = d0 + ty + i, s = s0 + tx;
    if (dh < VT_D) dst[(size_t)dh * S_LEN + s] = tile[tx][ty + i];
  }
}

// ---------------- xf = right_shift(x) + pos ----------------
__global__ __launch_bounds__(256) void build_xf(
    const float* __restrict__ x, const float* __restrict__ p0,
    const float* __restrict__ p1, const float* __restrict__ p2,
    float* __restrict__ xf) {
  int idx = blockIdx.x * 256 + threadIdx.x;
  int c4 = idx % 144;
  int s  = (idx / 144) & (S_LEN - 1);
  int b  = idx / (144 * S_LEN);
  int c  = c4 * 4;
  int t = s >> 8, hh = (s >> 4) & 15, w = s & 15;
  float4 pv;
  if (c < 192)       pv = *(const float4*)&p0[t  * 192 + c];
  else if (c < 384)  pv = *(const float4*)&p1[hh * 192 + c - 192];
  else               pv = *(const float4*)&p2[w  * 192 + c - 384];
  float4 xv = make_float4(0.f, 0.f, 0.f, 0.f);
  if (s > 0) xv = *(const float4*)&x[((size_t)b * S_LEN + s - 1) * CDIM + c];
  float4 r = make_float4(xv.x + pv.x, xv.y + pv.y, xv.z + pv.z, xv.w + pv.w);
  *(float4*)&xf[((size_t)b * S_LEN + s) * CDIM + c] = r;
}

// ---------------- LayerNorm (eps added to rsqrt, per reference) ----------------
__global__ __launch_bounds__(256) void ln_kernel(
    const float* __restrict__ x, const float* __restrict__ g,
    const float* __restrict__ b, bf16* __restrict__ out) {
  int row  = blockIdx.x * 4 + (threadIdx.x >> 6);
  int lane = threadIdx.x & 63;
  const float* xr = x + (size_t)row * CDIM;
  float vals[9];
  float sum = 0.f;
#pragma unroll
  for (int i = 0; i < 9; i++) { vals[i] = xr[lane + 64 * i]; sum += vals[i]; }
#pragma unroll
  for (int o = 1; o < 64; o <<= 1) sum += __shfl_xor(sum, o);
  float mu = sum * (1.f / CDIM);
  float vs = 0.f;
#pragma unroll
  for (int i = 0; i < 9; i++) { float d = vals[i] - mu; vs += d * d; }
#pragma unroll
  for (int o = 1; o < 64; o <<= 1) vs += __shfl_xor(vs, o);
  float mult = 1e-5f + rsqrtf(vs * (1.f / CDIM));
  bf16* orow = out + (size_t)row * CDIM;
#pragma unroll
  for (int i = 0; i < 9; i++) {
    int c = lane + 64 * i;
    orow[c] = __float2bfloat16((vals[i] - mu) * mult * g[c] + b[c]);
  }
}

// ---------------- GEMM v5: 64x64 tile, BK=64, dbuf, split-K atomics ----------------
// Fragment-linear LDS strips (16 rows x 32 k = 512 shorts; chunk l: row l&15,
// k (l>>4)*8) -> all ds ops lane-linear, conflict-free.
// SPLITK>1: fp32 atomicAdd into outp (residual pre-resident); bias from split 0.
template <int SPLITK, bool BIAS, int ACT, bool OUTBF>
__global__ __launch_bounds__(256) void gemm5(
    const bf16* __restrict__ A, const bf16* __restrict__ Bt,
    const float* __restrict__ bias, void* __restrict__ outp,
    int N, int Ktot) {
  const int Ks = Ktot / SPLITK;
  const int kbase = (SPLITK > 1) ? blockIdx.z * Ks : 0;
  __shared__ short ldsA[2][2][4][512];   // [buf][kc][strip][chunk]
  __shared__ short ldsB[2][2][4][512];
  const int tid = threadIdx.x, lane = tid & 63, wave = tid >> 6;
  const int lr = lane & 15, quad = lane >> 4;
  const int m0 = blockIdx.x * 64, n0 = blockIdx.y * 64;
  const int srow = wave * 16 + (tid & 15);       // staged row within tile
  const int skc  = ((tid >> 4) & 3) * 8;         // k sub-chunk 0/8/16/24
  const short* Ag = (const short*)A  + (size_t)(m0 + srow) * Ktot + kbase + skc;
  const short* Bg = (const short*)Bt + (size_t)(n0 + srow) * Ktot + kbase + skc;
  const int loff = lane * 8;
  f32x4 acc[2][2] = {};

  // prologue: stage k=0 into buffer 0
  *(bf16x8*)&ldsA[0][0][wave][loff] = *(const bf16x8*)(Ag);
  *(bf16x8*)&ldsA[0][1][wave][loff] = *(const bf16x8*)(Ag + 32);
  *(bf16x8*)&ldsB[0][0][wave][loff] = *(const bf16x8*)(Bg);
  *(bf16x8*)&ldsB[0][1][wave][loff] = *(const bf16x8*)(Bg + 32);
  __syncthreads();

  int buf = 0;
  for (int k0 = 0; k0 < Ks; k0 += 64, buf ^= 1) {
    const bool more = (k0 + 64) < Ks;
    bf16x8 na0, na1, nb0, nb1;
    if (more) {
      na0 = *(const bf16x8*)(Ag + k0 + 64);
      na1 = *(const bf16x8*)(Ag + k0 + 96);
      nb0 = *(const bf16x8*)(Bg + k0 + 64);
      nb1 = *(const bf16x8*)(Bg + k0 + 96);
    }
#pragma unroll
    for (int kc = 0; kc < 2; kc++) {
      bf16x8 af[2], bfv[2];
#pragma unroll
      for (int mi = 0; mi < 2; mi++)
        af[mi] = *(const bf16x8*)&ldsA[buf][kc][(wave & 1) * 2 + mi][loff];
#pragma unroll
      for (int ni = 0; ni < 2; ni++)
        bfv[ni] = *(const bf16x8*)&ldsB[buf][kc][(wave >> 1) * 2 + ni][loff];
#pragma unroll
      for (int mi = 0; mi < 2; mi++)
#pragma unroll
        for (int ni = 0; ni < 2; ni++)
          acc[mi][ni] = __builtin_amdgcn_mfma_f32_16x16x32_bf16(af[mi], bfv[ni], acc[mi][ni], 0, 0, 0);
    }
    if (more) {
      *(bf16x8*)&ldsA[buf ^ 1][0][wave][loff] = na0;
      *(bf16x8*)&ldsA[buf ^ 1][1][wave][loff] = na1;
      *(bf16x8*)&ldsB[buf ^ 1][0][wave][loff] = nb0;
      *(bf16x8*)&ldsB[buf ^ 1][1][wave][loff] = nb1;
    }
    __syncthreads();
  }

  float* fout = (float*)outp;
  bf16*  bout = (bf16*)outp;
#pragma unroll
  for (int mi = 0; mi < 2; mi++)
#pragma unroll
    for (int ni = 0; ni < 2; ni++) {
      int col = n0 + (wave >> 1) * 32 + ni * 16 + lr;
#pragma unroll
      for (int r = 0; r < 4; r++) {
        int row = m0 + (wave & 1) * 32 + mi * 16 + quad * 4 + r;
        float v = acc[mi][ni][r];
        if (BIAS && (SPLITK == 1 || blockIdx.z == 0)) v += bias[col];
        if (ACT == 1) v = v / (1.f + __expf(-1.702f * v));   // GeLU2
        size_t idx = (size_t)row * N + col;
        if (SPLITK > 1)      atomicAdd(&fout[idx], v);
        else if (OUTBF)      bout[idx] = __float2bfloat16(v);
        else                 fout[idx] = v;
      }
    }
}

// ---------------- MFMA flash attention v3: DMA-staged K and V^T ----------------
// grid (16, B*NH): qt = 15-bx (heavy first). qkv bf16 [4096][1728]; vT [bh][80][1024].
__global__ __launch_bounds__(256) void attn_mfma(
    const bf16* __restrict__ qkv, const bf16* __restrict__ vT,
    bf16* __restrict__ a) {
  __shared__ short ldsK[12 * 512];     // page (nc*3+c), lane-linear
  __shared__ short ldsV[10 * 512];     // page (dc*2+kc), lane-linear
  __shared__ short ldsP[4 * 1024];     // per-wave, fragment-linear (2 kc pages)
  const int bh = blockIdx.y, b = bh >> 3, h = bh & 7;
  const int tid = threadIdx.x, wave = tid >> 6, lane = tid & 63;
  const int lr = lane & 15, quad = lane >> 4;
  const int qt = 15 - (int)blockIdx.x;
  const float scale = 0.11785113019775793f;  // 1/sqrt(72)
  const int qcol = h * DKH, kcol = CDIM + h * DKH;

  const int qrow = qt * 64 + wave * 16 + lr;
  const short* qg = (const short*)qkv + (size_t)(b * S_LEN + qrow) * QKVN + qcol;
  bf16x8 qfrag[3];
#pragma unroll
  for (int c = 0; c < 3; c++) {
    int d0 = c * 32 + quad * 8;
    bf16x8 z = {0, 0, 0, 0, 0, 0, 0, 0};
    qfrag[c] = (d0 < DKH) ? *(const bf16x8*)(qg + d0) : z;
  }
  f32x4 oacc[5] = {};
  float m[4], l[4];
#pragma unroll
  for (int r = 0; r < 4; r++) { m[r] = -1e30f; l[r] = 0.f; }

  const short* vtb = (const short*)vT + (size_t)bh * VT_LS;

  for (int kt = 0; kt <= qt; kt++) {
    __syncthreads();
    // K pages: wave stages keys nc=wave, 3 d-pages (lane-linear dest)
    {
      const short* kg = (const short*)qkv +
          (size_t)(b * S_LEN + kt * 64 + wave * 16 + lr) * QKVN + kcol + quad * 8;
#pragma unroll
      for (int c = 0; c < 3; c++)
        gload16(kg + c * 32, &ldsK[(wave * 3 + c) * 512]);
    }
    // V^T pages: page p=(dc*2+kc): chunk l = d dc*16+(l&15), keys kc*32+(l>>4)*8..+7
#pragma unroll
    for (int p = wave; p < 10; p += 4) {
      int dc = p >> 1, kc = p & 1;
      const short* vg = vtb + (size_t)(dc * 16 + lr) * S_LEN + kt * 64 + kc * 32 + quad * 8;
      gload16(vg, &ldsV[p * 512]);
    }
    __syncthreads();
    // S = Q K^T
    f32x4 sacc[4] = {};
#pragma unroll
    for (int nc = 0; nc < 4; nc++)
#pragma unroll
      for (int c = 0; c < 3; c++) {
        bf16x8 kf = *(const bf16x8*)&ldsK[(nc * 3 + c) * 512 + lane * 8];
        sacc[nc] = __builtin_amdgcn_mfma_f32_16x16x32_bf16(qfrag[c], kf, sacc[nc], 0, 0, 0);
      }
    // scale + causal mask + online softmax
    float tmax[4];
#pragma unroll
    for (int r = 0; r < 4; r++) tmax[r] = -1e30f;
    bool diag = (kt == qt);
#pragma unroll
    for (int nc = 0; nc < 4; nc++)
#pragma unroll
      for (int r = 0; r < 4; r++) {
        float s = sacc[nc][r] * scale;
        if (diag && (nc * 16 + lr > wave * 16 + quad * 4 + r)) s = -1e30f;
        sacc[nc][r] = s;
        tmax[r] = fmaxf(tmax[r], s);
      }
#pragma unroll
    for (int r = 0; r < 4; r++) {
      tmax[r] = fmaxf(tmax[r], __shfl_xor(tmax[r], 1));
      tmax[r] = fmaxf(tmax[r], __shfl_xor(tmax[r], 2));
      tmax[r] = fmaxf(tmax[r], __shfl_xor(tmax[r], 4));
      tmax[r] = fmaxf(tmax[r], __shfl_xor(tmax[r], 8));
    }
    float alpha[4], psum[4];
#pragma unroll
    for (int r = 0; r < 4; r++) {
      float mn = fmaxf(m[r], tmax[r]);
      alpha[r] = __expf(m[r] - mn);
      m[r] = mn;
      psum[r] = 0.f;
    }
#pragma unroll
    for (int nc = 0; nc < 4; nc++)
#pragma unroll
      for (int r = 0; r < 4; r++) {
        float p = __expf(sacc[nc][r] - m[r]);
        psum[r] += p;
        int col = nc * 16 + lr;
        ldsP[wave * 1024 + (col >> 5) * 512 +
             (((col >> 3) & 3) * 16 + quad * 4 + r) * 8 + (col & 7)] = f2bf_bits(p);
      }
#pragma unroll
    for (int r = 0; r < 4; r++) {
      psum[r] += __shfl_xor(psum[r], 1);
      psum[r] += __shfl_xor(psum[r], 2);
      psum[r] += __shfl_xor(psum[r], 4);
      psum[r] += __shfl_xor(psum[r], 8);
      l[r] = l[r] * alpha[r] + psum[r];
    }
#pragma unroll
    for (int dc = 0; dc < 5; dc++)
#pragma unroll
      for (int r = 0; r < 4; r++) oacc[dc][r] *= alpha[r];
    __builtin_amdgcn_sched_barrier(0);
    // O += P V
    bf16x8 pfrag[2];
#pragma unroll
    for (int kc = 0; kc < 2; kc++)
      pfrag[kc] = *(const bf16x8*)&ldsP[wave * 1024 + kc * 512 + lane * 8];
#pragma unroll
    for (int dc = 0; dc < 5; dc++)
#pragma unroll
      for (int kc = 0; kc < 2; kc++) {
        bf16x8 vf = *(const bf16x8*)&ldsV[(dc * 2 + kc) * 512 + lane * 8];
        oacc[dc] = __builtin_amdgcn_mfma_f32_16x16x32_bf16(pfrag[kc], vf, oacc[dc], 0, 0, 0);
      }
  }  // kt

#pragma unroll
  for (int dc = 0; dc < 5; dc++) {
    int d = dc * 16 + lr;
    if (d < DKH) {
#pragma unroll
      for (int r = 0; r < 4; r++) {
        int row = qt * 64 + wave * 16 + quad * 4 + r;
        float val = oacc[dc][r] / l[r];
        a[(size_t)(b * S_LEN + row) * CDIM + h * DKH + d] = __float2bfloat16(val);
      }
    }
  }
}

// ---------------- launch ----------------
extern "C" void kernel_launch(void* const* d_in, const int* in_sizes, int n_in,
                              void* d_out, int out_size, void* d_ws, size_t ws_size,
                              hipStream_t stream) {
  const float* x    = (const float*)d_in[0];
  const float* pos0 = (const float*)d_in[1];
  const float* pos1 = (const float*)d_in[2];
  const float* pos2 = (const float*)d_in[3];
  const float* ln1g = (const float*)d_in[4];
  const float* ln1b = (const float*)d_in[5];
  const float* wq   = (const float*)d_in[6];
  const float* wk   = (const float*)d_in[7];
  const float* wv   = (const float*)d_in[8];
  const float* wo   = (const float*)d_in[9];
  const float* wob  = (const float*)d_in[10];
  const float* ln2g = (const float*)d_in[11];
  const float* ln2b = (const float*)d_in[12];
  const float* w1   = (const float*)d_in[13];
  const float* b1   = (const float*)d_in[14];
  const float* w2   = (const float*)d_in[15];
  const float* b2   = (const float*)d_in[16];

  char* ws = (char*)d_ws;
  size_t off = 0;
  auto alloc = [&](size_t bytes) {
    char* p = ws + off;
    off += (bytes + 255) & ~(size_t)255;
    return p;
  };
  const size_t ils  = (size_t)CDIM * CDIM;
  const size_t ils2 = (size_t)CDIM * FFDIM;
  const size_t qkv_ls = (size_t)QKVN * CDIM;
  bf16* wqkvT = (bf16*)alloc(4 * qkv_ls * sizeof(bf16));
  bf16* woT   = (bf16*)alloc(4 * ils * sizeof(bf16));
  bf16* w1T   = (bf16*)alloc(4 * ils2 * sizeof(bf16));
  bf16* w2T   = (bf16*)alloc(4 * ils2 * sizeof(bf16));
  bf16* hbuf  = (bf16*)alloc((size_t)MROWS * CDIM * sizeof(bf16));
  bf16* abuf  = (bf16*)alloc((size_t)MROWS * CDIM * sizeof(bf16));
  bf16* ubuf  = (bf16*)alloc((size_t)MROWS * FFDIM * sizeof(bf16));
  bf16* qkvb  = (bf16*)alloc((size_t)MROWS * QKVN * sizeof(bf16));
  bf16* vTb   = (bf16*)alloc((size_t)32 * VT_LS * sizeof(bf16));
  float* xf   = (float*)d_out;   // residual stream lives in d_out (fp32)

  transpose_cvt<<<dim3(18, 18, 4), 256, 0, stream>>>(wq, wqkvT, CDIM, CDIM, ils, qkv_ls);
  transpose_cvt<<<dim3(18, 18, 4), 256, 0, stream>>>(wk, wqkvT + ils, CDIM, CDIM, ils, qkv_ls);
  transpose_cvt<<<dim3(18, 18, 4), 256, 0, stream>>>(wv, wqkvT + 2 * ils, CDIM, CDIM, ils, qkv_ls);
  transpose_cvt<<<dim3(18, 18, 4), 256, 0, stream>>>(wo, woT, CDIM, CDIM, ils, ils);
  transpose_cvt<<<dim3(72, 18, 4), 256, 0, stream>>>(w1, w1T, CDIM, FFDIM, ils2, ils2);
  transpose_cvt<<<dim3(18, 72, 4), 256, 0, stream>>>(w2, w2T, FFDIM, CDIM, ils2, ils2);

  build_xf<<<2304, 256, 0, stream>>>(x, pos0, pos1, pos2, xf);

  for (int l = 0; l < 4; l++) {
    bf16* wqkv_l = wqkvT + (size_t)l * qkv_ls;
    bf16* wo_l   = woT   + (size_t)l * ils;
    bf16* w1_l   = w1T   + (size_t)l * ils2;
    bf16* w2_l   = w2T   + (size_t)l * ils2;

    ln_kernel<<<1024, 256, 0, stream>>>(xf, ln1g + l * CDIM, ln1b + l * CDIM, hbuf);
    // fused QKV: 4096x1728x576, 1728 blocks
    gemm5<1, false, 0, true><<<dim3(64, 27, 1), 256, 0, stream>>>(
        hbuf, wqkv_l, nullptr, qkvb, QKVN, CDIM);
    vt_kernel<<<dim3(32, 3, 32), 256, 0, stream>>>(qkvb, vTb);
    attn_mfma<<<dim3(16, 32), 256, 0, stream>>>(qkvb, vTb, abuf);
    // proj: split-K=3 atomic into xf (residual resident), bias from split 0
    gemm5<3, true, 0, false><<<dim3(64, 9, 3), 256, 0, stream>>>(
        abuf, wo_l, wob + l * CDIM, xf, CDIM, CDIM);
    ln_kernel<<<1024, 256, 0, stream>>>(xf, ln2g + l * CDIM, ln2b + l * CDIM, hbuf);
    // FFN1 + bias + GeLU2: 4096x2304x576, 2304 blocks
    gemm5<1, true, 1, true><<<dim3(64, 36, 1), 256, 0, stream>>>(
        hbuf, w1_l, b1 + l * FFDIM, ubuf, FFDIM, CDIM);
    // FFN2: split-K=4 atomic into xf, bias from split 0
    gemm5<4, true, 0, false><<<dim3(64, 9, 4), 256, 0, stream>>>(
        ubuf, w2_l, b2 + l * CDIM, xf, CDIM, FFDIM);
  }
}

// Round 10
// 1004.067 us; speedup vs baseline: 1.0025x; 1.0025x over previous
//
#include <hip/hip_runtime.h>
#include <hip/hip_bf16.h>

typedef __hip_bfloat16 bf16;
using bf16x8 = __attribute__((ext_vector_type(8))) short;
using f32x4  = __attribute__((ext_vector_type(4))) float;

#define S_LEN 1024
#define CDIM  576
#define NHEAD 8
#define DKH   72
#define BATCH 4
#define MROWS 4096   // B*S
#define FFDIM 2304
#define QKVN  1728   // 3*C
#define VT_D  80     // vT padded d
#define VT_LS (VT_D * S_LEN)

// async global->LDS, 16B per lane, lane-ordered LDS destination
__device__ __forceinline__ void gload16(const void* g, void* l) {
  __builtin_amdgcn_global_load_lds(
      (const __attribute__((address_space(1))) unsigned int*)g,
      (__attribute__((address_space(3))) unsigned int*)l, 16, 0, 0);
}

// float -> bf16 bits (RNE), pure integer math (type-safe for LDS punning)
__device__ __forceinline__ short f2bf_bits(float x) {
  unsigned int u = __float_as_uint(x);
  u += 0x7fffu + ((u >> 16) & 1u);
  return (short)(u >> 16);
}

// ---------------- weight transpose + fp32->bf16 convert ----------------
__global__ __launch_bounds__(256) void transpose_cvt(
    const float* __restrict__ in, bf16* __restrict__ out, int K, int N,
    size_t in_ls, size_t out_ls) {
  __shared__ float tile[32][33];
  const float* inl = in + (size_t)blockIdx.z * in_ls;
  bf16* outl = out + (size_t)blockIdx.z * out_ls;
  int n0 = blockIdx.x * 32, k0 = blockIdx.y * 32;
  int tx = threadIdx.x & 31, ty = threadIdx.x >> 5;
#pragma unroll
  for (int i = 0; i < 32; i += 8)
    tile[ty + i][tx] = inl[(size_t)(k0 + ty + i) * N + (n0 + tx)];
  __syncthreads();
#pragma unroll
  for (int i = 0; i < 32; i += 8)
    outl[(size_t)(n0 + ty + i) * K + (k0 + tx)] = __float2bfloat16(tile[tx][ty + i]);
}

// ---------------- V^T builder: qkvb V-slice [s][dh] -> vT [bh][dh][s] ----------------
__global__ __launch_bounds__(256) void vt_kernel(
    const bf16* __restrict__ qkvb, bf16* __restrict__ vT) {
  __shared__ short tile[32][33];
  int bh = blockIdx.z, b = bh >> 3, h = bh & 7;
  int s0 = blockIdx.x * 32, d0 = blockIdx.y * 32;
  int tx = threadIdx.x & 31, ty = threadIdx.x >> 5;
  const short* src = (const short*)qkvb;
  short* dst = (short*)vT + (size_t)bh * VT_LS;
#pragma unroll
  for (int i = 0; i < 32; i += 8) {
    int s = s0 + ty + i, dh = d0 + tx;
    short v = 0;
    if (dh < DKH) v = src[(size_t)(b * S_LEN + s) * QKVN + 2 * CDIM + h * DKH + dh];
    tile[ty + i][tx] = v;
  }
  __syncthreads();
#pragma unroll
  for (int i = 0; i < 32; i += 8) {
    int dh = d0 + ty + i, s = s0 + tx;
    if (dh < VT_D) dst[(size_t)dh * S_LEN + s] = tile[tx][ty + i];
  }
}

// ---------------- xf = right_shift(x) + pos ----------------
__global__ __launch_bounds__(256) void build_xf(
    const float* __restrict__ x, const float* __restrict__ p0,
    const float* __restrict__ p1, const float* __restrict__ p2,
    float* __restrict__ xf) {
  int idx = blockIdx.x * 256 + threadIdx.x;
  int c4 = idx % 144;
  int s  = (idx / 144) & (S_LEN - 1);
  int b  = idx / (144 * S_LEN);
  int c  = c4 * 4;
  int t = s >> 8, hh = (s >> 4) & 15, w = s & 15;
  float4 pv;
  if (c < 192)       pv = *(const float4*)&p0[t  * 192 + c];
  else if (c < 384)  pv = *(const float4*)&p1[hh * 192 + c - 192];
  else               pv = *(const float4*)&p2[w  * 192 + c - 384];
  float4 xv = make_float4(0.f, 0.f, 0.f, 0.f);
  if (s > 0) xv = *(const float4*)&x[((size_t)b * S_LEN + s - 1) * CDIM + c];
  float4 r = make_float4(xv.x + pv.x, xv.y + pv.y, xv.z + pv.z, xv.w + pv.w);
  *(float4*)&xf[((size_t)b * S_LEN + s) * CDIM + c] = r;
}

// ---------------- LayerNorm (eps added to rsqrt, per reference) ----------------
__global__ __launch_bounds__(256) void ln_kernel(
    const float* __restrict__ x, const float* __restrict__ g,
    const float* __restrict__ b, bf16* __restrict__ out) {
  int row  = blockIdx.x * 4 + (threadIdx.x >> 6);
  int lane = threadIdx.x & 63;
  const float* xr = x + (size_t)row * CDIM;
  float vals[9];
  float sum = 0.f;
#pragma unroll
  for (int i = 0; i < 9; i++) { vals[i] = xr[lane + 64 * i]; sum += vals[i]; }
#pragma unroll
  for (int o = 1; o < 64; o <<= 1) sum += __shfl_xor(sum, o);
  float mu = sum * (1.f / CDIM);
  float vs = 0.f;
#pragma unroll
  for (int i = 0; i < 9; i++) { float d = vals[i] - mu; vs += d * d; }
#pragma unroll
  for (int o = 1; o < 64; o <<= 1) vs += __shfl_xor(vs, o);
  float mult = 1e-5f + rsqrtf(vs * (1.f / CDIM));
  bf16* orow = out + (size_t)row * CDIM;
#pragma unroll
  for (int i = 0; i < 9; i++) {
    int c = lane + 64 * i;
    orow[c] = __float2bfloat16((vals[i] - mu) * mult * g[c] + b[c]);
  }
}

// ---------------- GEMM v6: BMx64 tile, BK=64, dbuf, fragment-linear LDS ----------------
// BM=64: 4 waves 2x2 (8 MFMA/iter/wave). BM=32: 4 waves n-split (4 MFMA/iter/wave),
// double the grid for latency overlap on small-N GEMMs. No atomics.
template <int BM, bool BIAS, bool RES, int ACT, bool OUTBF>
__global__ __launch_bounds__(256) void gemm6(
    const bf16* __restrict__ A, const bf16* __restrict__ Bt,
    const float* __restrict__ bias, const float* __restrict__ res,
    void* __restrict__ outp, int N, int K) {
  constexpr int MSTR = BM / 16;
  constexpr int MI = BM == 64 ? 2 : 2;   // m-frags per wave
  constexpr int NI = BM == 64 ? 2 : 1;   // n-frags per wave
  __shared__ short ldsA[2][2][MSTR][512];   // [buf][kc][strip][chunk]
  __shared__ short ldsB[2][2][4][512];
  const int tid = threadIdx.x, lane = tid & 63, wave = tid >> 6;
  const int lr = lane & 15, quad = lane >> 4;
  const int m0 = blockIdx.x * BM, n0 = blockIdx.y * 64;
  // staging roles (fragment-linear: strip chunk l -> row l&15, k (l>>4)*8)
  const bool doA = (BM == 64) || (tid < 128);
  const int aStrip = (BM == 64) ? wave : (tid >> 6);   // 0..MSTR-1
  const int aLane = tid & 63;
  const short* Ag = (const short*)A +
      (size_t)(m0 + aStrip * 16 + (aLane & 15)) * K + ((aLane >> 4) & 3) * 8;
  const short* Bg = (const short*)Bt +
      (size_t)(n0 + wave * 16 + lr) * K + ((lane >> 4) & 3) * 8;
  const int aoff = aLane * 8, boff = lane * 8;
  f32x4 acc[MI][NI] = {};

  // prologue: stage k=0 into buffer 0
  if (doA) {
    *(bf16x8*)&ldsA[0][0][aStrip][aoff] = *(const bf16x8*)(Ag);
    *(bf16x8*)&ldsA[0][1][aStrip][aoff] = *(const bf16x8*)(Ag + 32);
  }
  *(bf16x8*)&ldsB[0][0][wave][boff] = *(const bf16x8*)(Bg);
  *(bf16x8*)&ldsB[0][1][wave][boff] = *(const bf16x8*)(Bg + 32);
  __syncthreads();

  int buf = 0;
  for (int k0 = 0; k0 < K; k0 += 64, buf ^= 1) {
    const bool more = (k0 + 64) < K;
    bf16x8 na0, na1, nb0, nb1;
    if (more) {
      if (doA) {
        na0 = *(const bf16x8*)(Ag + k0 + 64);
        na1 = *(const bf16x8*)(Ag + k0 + 96);
      }
      nb0 = *(const bf16x8*)(Bg + k0 + 64);
      nb1 = *(const bf16x8*)(Bg + k0 + 96);
    }
#pragma unroll
    for (int kc = 0; kc < 2; kc++) {
      bf16x8 af[MI], bfv[NI];
#pragma unroll
      for (int mi = 0; mi < MI; mi++)
        af[mi] = *(const bf16x8*)&ldsA[buf][kc][(BM == 64 ? (wave & 1) * 2 : 0) + mi][lane * 8];
#pragma unroll
      for (int ni = 0; ni < NI; ni++)
        bfv[ni] = *(const bf16x8*)&ldsB[buf][kc][(BM == 64 ? (wave >> 1) * 2 + ni : wave)][lane * 8];
#pragma unroll
      for (int mi = 0; mi < MI; mi++)
#pragma unroll
        for (int ni = 0; ni < NI; ni++)
          acc[mi][ni] = __builtin_amdgcn_mfma_f32_16x16x32_bf16(af[mi], bfv[ni], acc[mi][ni], 0, 0, 0);
    }
    if (more) {
      if (doA) {
        *(bf16x8*)&ldsA[buf ^ 1][0][aStrip][aoff] = na0;
        *(bf16x8*)&ldsA[buf ^ 1][1][aStrip][aoff] = na1;
      }
      *(bf16x8*)&ldsB[buf ^ 1][0][wave][boff] = nb0;
      *(bf16x8*)&ldsB[buf ^ 1][1][wave][boff] = nb1;
    }
    __syncthreads();
  }

  float* fout = (float*)outp;
  bf16*  bout = (bf16*)outp;
#pragma unroll
  for (int mi = 0; mi < MI; mi++)
#pragma unroll
    for (int ni = 0; ni < NI; ni++) {
      int col = (BM == 64) ? (n0 + (wave >> 1) * 32 + ni * 16 + lr)
                           : (n0 + wave * 16 + lr);
#pragma unroll
      for (int r = 0; r < 4; r++) {
        int row = (BM == 64) ? (m0 + (wave & 1) * 32 + mi * 16 + quad * 4 + r)
                             : (m0 + mi * 16 + quad * 4 + r);
        float v = acc[mi][ni][r];
        if (BIAS) v += bias[col];
        if (ACT == 1) v = v / (1.f + __expf(-1.702f * v));   // GeLU2
        size_t idx = (size_t)row * N + col;
        if (RES) v += res[idx];
        if (OUTBF) bout[idx] = __float2bfloat16(v);
        else       fout[idx] = v;
      }
    }
}

// ---------------- MFMA flash attention v3: DMA-staged K and V^T, balanced ----------------
// grid (16, B*NH). qt = bx&1 ? bx>>1 : 15-(bx>>1): consecutive block pairs sum to 17 tiles.
__global__ __launch_bounds__(256) void attn_mfma(
    const bf16* __restrict__ qkv, const bf16* __restrict__ vT,
    bf16* __restrict__ a) {
  __shared__ short ldsK[12 * 512];     // page (nc*3+c), lane-linear
  __shared__ short ldsV[10 * 512];     // page (dc*2+kc), lane-linear
  __shared__ short ldsP[4 * 1024];     // per-wave, fragment-linear (2 kc pages)
  const int bh = blockIdx.y, b = bh >> 3, h = bh & 7;
  const int tid = threadIdx.x, wave = tid >> 6, lane = tid & 63;
  const int lr = lane & 15, quad = lane >> 4;
  const int bx = blockIdx.x;
  const int qt = (bx & 1) ? (bx >> 1) : (15 - (bx >> 1));
  const float scale = 0.11785113019775793f;  // 1/sqrt(72)
  const int qcol = h * DKH, kcol = CDIM + h * DKH;

  const int qrow = qt * 64 + wave * 16 + lr;
  const short* qg = (const short*)qkv + (size_t)(b * S_LEN + qrow) * QKVN + qcol;
  bf16x8 qfrag[3];
#pragma unroll
  for (int c = 0; c < 3; c++) {
    int d0 = c * 32 + quad * 8;
    bf16x8 z = {0, 0, 0, 0, 0, 0, 0, 0};
    qfrag[c] = (d0 < DKH) ? *(const bf16x8*)(qg + d0) : z;
  }
  f32x4 oacc[5] = {};
  float m[4], l[4];
#pragma unroll
  for (int r = 0; r < 4; r++) { m[r] = -1e30f; l[r] = 0.f; }

  const short* vtb = (const short*)vT + (size_t)bh * VT_LS;

  for (int kt = 0; kt <= qt; kt++) {
    __syncthreads();
    {
      const short* kg = (const short*)qkv +
          (size_t)(b * S_LEN + kt * 64 + wave * 16 + lr) * QKVN + kcol + quad * 8;
#pragma unroll
      for (int c = 0; c < 3; c++)
        gload16(kg + c * 32, &ldsK[(wave * 3 + c) * 512]);
    }
#pragma unroll
    for (int p = wave; p < 10; p += 4) {
      int dc = p >> 1, kc = p & 1;
      const short* vg = vtb + (size_t)(dc * 16 + lr) * S_LEN + kt * 64 + kc * 32 + quad * 8;
      gload16(vg, &ldsV[p * 512]);
    }
    __syncthreads();
    f32x4 sacc[4] = {};
#pragma unroll
    for (int nc = 0; nc < 4; nc++)
#pragma unroll
      for (int c = 0; c < 3; c++) {
        bf16x8 kf = *(const bf16x8*)&ldsK[(nc * 3 + c) * 512 + lane * 8];
        sacc[nc] = __builtin_amdgcn_mfma_f32_16x16x32_bf16(qfrag[c], kf, sacc[nc], 0, 0, 0);
      }
    float tmax[4];
#pragma unroll
    for (int r = 0; r < 4; r++) tmax[r] = -1e30f;
    bool diag = (kt == qt);
#pragma unroll
    for (int nc = 0; nc < 4; nc++)
#pragma unroll
      for (int r = 0; r < 4; r++) {
        float s = sacc[nc][r] * scale;
        if (diag && (nc * 16 + lr > wave * 16 + quad * 4 + r)) s = -1e30f;
        sacc[nc][r] = s;
        tmax[r] = fmaxf(tmax[r], s);
      }
#pragma unroll
    for (int r = 0; r < 4; r++) {
      tmax[r] = fmaxf(tmax[r], __shfl_xor(tmax[r], 1));
      tmax[r] = fmaxf(tmax[r], __shfl_xor(tmax[r], 2));
      tmax[r] = fmaxf(tmax[r], __shfl_xor(tmax[r], 4));
      tmax[r] = fmaxf(tmax[r], __shfl_xor(tmax[r], 8));
    }
    float alpha[4], psum[4];
#pragma unroll
    for (int r = 0; r < 4; r++) {
      float mn = fmaxf(m[r], tmax[r]);
      alpha[r] = __expf(m[r] - mn);
      m[r] = mn;
      psum[r] = 0.f;
    }
#pragma unroll
    for (int nc = 0; nc < 4; nc++)
#pragma unroll
      for (int r = 0; r < 4; r++) {
        float p = __expf(sacc[nc][r] - m[r]);
        psum[r] += p;
        int col = nc * 16 + lr;
        ldsP[wave * 1024 + (col >> 5) * 512 +
             (((col >> 3) & 3) * 16 + quad * 4 + r) * 8 + (col & 7)] = f2bf_bits(p);
      }
#pragma unroll
    for (int r = 0; r < 4; r++) {
      psum[r] += __shfl_xor(psum[r], 1);
      psum[r] += __shfl_xor(psum[r], 2);
      psum[r] += __shfl_xor(psum[r], 4);
      psum[r] += __shfl_xor(psum[r], 8);
      l[r] = l[r] * alpha[r] + psum[r];
    }
#pragma unroll
    for (int dc = 0; dc < 5; dc++)
#pragma unroll
      for (int r = 0; r < 4; r++) oacc[dc][r] *= alpha[r];
    __builtin_amdgcn_sched_barrier(0);
    bf16x8 pfrag[2];
#pragma unroll
    for (int kc = 0; kc < 2; kc++)
      pfrag[kc] = *(const bf16x8*)&ldsP[wave * 1024 + kc * 512 + lane * 8];
#pragma unroll
    for (int dc = 0; dc < 5; dc++)
#pragma unroll
      for (int kc = 0; kc < 2; kc++) {
        bf16x8 vf = *(const bf16x8*)&ldsV[(dc * 2 + kc) * 512 + lane * 8];
        oacc[dc] = __builtin_amdgcn_mfma_f32_16x16x32_bf16(pfrag[kc], vf, oacc[dc], 0, 0, 0);
      }
  }  // kt

#pragma unroll
  for (int dc = 0; dc < 5; dc++) {
    int d = dc * 16 + lr;
    if (d < DKH) {
#pragma unroll
      for (int r = 0; r < 4; r++) {
        int row = qt * 64 + wave * 16 + quad * 4 + r;
        float val = oacc[dc][r] / l[r];
        a[(size_t)(b * S_LEN + row) * CDIM + h * DKH + d] = __float2bfloat16(val);
      }
    }
  }
}

// ---------------- launch ----------------
extern "C" void kernel_launch(void* const* d_in, const int* in_sizes, int n_in,
                              void* d_out, int out_size, void* d_ws, size_t ws_size,
                              hipStream_t stream) {
  const float* x    = (const float*)d_in[0];
  const float* pos0 = (const float*)d_in[1];
  const float* pos1 = (const float*)d_in[2];
  const float* pos2 = (const float*)d_in[3];
  const float* ln1g = (const float*)d_in[4];
  const float* ln1b = (const float*)d_in[5];
  const float* wq   = (const float*)d_in[6];
  const float* wk   = (const float*)d_in[7];
  const float* wv   = (const float*)d_in[8];
  const float* wo   = (const float*)d_in[9];
  const float* wob  = (const float*)d_in[10];
  const float* ln2g = (const float*)d_in[11];
  const float* ln2b = (const float*)d_in[12];
  const float* w1   = (const float*)d_in[13];
  const float* b1   = (const float*)d_in[14];
  const float* w2   = (const float*)d_in[15];
  const float* b2   = (const float*)d_in[16];

  char* ws = (char*)d_ws;
  size_t off = 0;
  auto alloc = [&](size_t bytes) {
    char* p = ws + off;
    off += (bytes + 255) & ~(size_t)255;
    return p;
  };
  const size_t ils  = (size_t)CDIM * CDIM;
  const size_t ils2 = (size_t)CDIM * FFDIM;
  const size_t qkv_ls = (size_t)QKVN * CDIM;
  bf16* wqkvT = (bf16*)alloc(4 * qkv_ls * sizeof(bf16));
  bf16* woT   = (bf16*)alloc(4 * ils * sizeof(bf16));
  bf16* w1T   = (bf16*)alloc(4 * ils2 * sizeof(bf16));
  bf16* w2T   = (bf16*)alloc(4 * ils2 * sizeof(bf16));
  bf16* hbuf  = (bf16*)alloc((size_t)MROWS * CDIM * sizeof(bf16));
  bf16* abuf  = (bf16*)alloc((size_t)MROWS * CDIM * sizeof(bf16));
  bf16* ubuf  = (bf16*)alloc((size_t)MROWS * FFDIM * sizeof(bf16));
  bf16* qkvb  = (bf16*)alloc((size_t)MROWS * QKVN * sizeof(bf16));
  bf16* vTb   = (bf16*)alloc((size_t)32 * VT_LS * sizeof(bf16));
  float* xf   = (float*)d_out;   // residual stream lives in d_out (fp32)

  transpose_cvt<<<dim3(18, 18, 4), 256, 0, stream>>>(wq, wqkvT, CDIM, CDIM, ils, qkv_ls);
  transpose_cvt<<<dim3(18, 18, 4), 256, 0, stream>>>(wk, wqkvT + ils, CDIM, CDIM, ils, qkv_ls);
  transpose_cvt<<<dim3(18, 18, 4), 256, 0, stream>>>(wv, wqkvT + 2 * ils, CDIM, CDIM, ils, qkv_ls);
  transpose_cvt<<<dim3(18, 18, 4), 256, 0, stream>>>(wo, woT, CDIM, CDIM, ils, ils);
  transpose_cvt<<<dim3(72, 18, 4), 256, 0, stream>>>(w1, w1T, CDIM, FFDIM, ils2, ils2);
  transpose_cvt<<<dim3(18, 72, 4), 256, 0, stream>>>(w2, w2T, FFDIM, CDIM, ils2, ils2);

  build_xf<<<2304, 256, 0, stream>>>(x, pos0, pos1, pos2, xf);

  for (int l = 0; l < 4; l++) {
    bf16* wqkv_l = wqkvT + (size_t)l * qkv_ls;
    bf16* wo_l   = woT   + (size_t)l * ils;
    bf16* w1_l   = w1T   + (size_t)l * ils2;
    bf16* w2_l   = w2T   + (size_t)l * ils2;

    ln_kernel<<<1024, 256, 0, stream>>>(xf, ln1g + l * CDIM, ln1b + l * CDIM, hbuf);
    // fused QKV: 4096x1728x576, BM=64, 1728 blocks
    gemm6<64, false, false, 0, true><<<dim3(64, 27), 256, 0, stream>>>(
        hbuf, wqkv_l, nullptr, nullptr, qkvb, QKVN, CDIM);
    vt_kernel<<<dim3(32, 3, 32), 256, 0, stream>>>(qkvb, vTb);
    attn_mfma<<<dim3(16, 32), 256, 0, stream>>>(qkvb, vTb, abuf);
    // proj + bias + residual: BM=32, 1152 blocks
    gemm6<32, true, true, 0, false><<<dim3(128, 9), 256, 0, stream>>>(
        abuf, wo_l, wob + l * CDIM, xf, xf, CDIM, CDIM);
    ln_kernel<<<1024, 256, 0, stream>>>(xf, ln2g + l * CDIM, ln2b + l * CDIM, hbuf);
    // FFN1 + bias + GeLU2: BM=64, 2304 blocks
    gemm6<64, true, false, 1, true><<<dim3(64, 36), 256, 0, stream>>>(
        hbuf, w1_l, b1 + l * FFDIM, nullptr, ubuf, FFDIM, CDIM);
    // FFN2 + bias + residual: BM=32, 1152 blocks
    gemm6<32, true, true, 0, false><<<dim3(128, 9), 256, 0, stream>>>(
        ubuf, w2_l, b2 + l * CDIM, xf, xf, CDIM, FFDIM);
  }
}